// Round 11
// baseline (300.844 us; speedup 1.0000x reference)
//
#include <hip/hip_runtime.h>

#define N_NODES 100000
#define N_EDGES 1600000
#define C 128
#define SCAN_B 1024
#define LDW 264            // padded LDS row stride (ushorts) for W staging

// bucket sort params
#define BSH 7              // bucket = dst >> 7 (128 nodes/bucket)
#define NBUCK 782          // ceil(100000 / 128)
#define BCAP 2560          // mean 2048, sigma 45 -> +11 sigma
#define TILE1 8192         // edges per phase-1 block
#define NBLK1 196          // ceil(1.6M / 8192)

typedef __attribute__((ext_vector_type(8))) short bfrag;   // 8 bf16 / 16 B
typedef __attribute__((ext_vector_type(4))) float f32x4;   // MFMA acc

// ---------- bf16 helpers ----------
__device__ __forceinline__ ushort f2b(float x) {
    uint u = __builtin_bit_cast(uint, x);
    u += 0x7fffu + ((u >> 16) & 1u);            // round-to-nearest-even
    return (ushort)(u >> 16);
}

// ---------------- CSR build: 2-phase bucket sort ----------------

__global__ __launch_bounds__(256) void bucket_scatter2_k(
        const int* __restrict__ ei, uint* __restrict__ buck, int* __restrict__ bcur) {
    __shared__ int hist[NBUCK];
    __shared__ int base_l[NBUCK];
    int t = threadIdx.x;
    int tile0 = blockIdx.x * TILE1;

    for (int i = t; i < NBUCK; i += 256) hist[i] = 0;
    __syncthreads();
    #pragma unroll 4
    for (int j = 0; j < TILE1 / 256; ++j) {
        int e = tile0 + j * 256 + t;
        if (e < N_EDGES) atomicAdd(&hist[ei[N_EDGES + e] >> BSH], 1);
    }
    __syncthreads();
    for (int i = t; i < NBUCK; i += 256) {
        int h = hist[i];
        base_l[i] = h ? atomicAdd(&bcur[i], h) : 0;
    }
    __syncthreads();
    for (int i = t; i < NBUCK; i += 256) hist[i] = 0;
    __syncthreads();
    #pragma unroll 4
    for (int j = 0; j < TILE1 / 256; ++j) {
        int e = tile0 + j * 256 + t;
        if (e < N_EDGES) {
            int src = ei[e];
            int dst = ei[N_EDGES + e];
            int b = dst >> BSH;
            int r = base_l[b] + atomicAdd(&hist[b], 1);
            if (r < BCAP) buck[(uint)b * BCAP + r] = (uint)src | ((uint)(dst & 127) << 17);
        }
    }
}

__global__ __launch_bounds__(256) void bucket_hist2_k(
        const uint* __restrict__ buck, const int* __restrict__ bcur, int* __restrict__ deg) {
    __shared__ int cnt_l[128];
    int b = blockIdx.x, t = threadIdx.x;
    if (t < 128) cnt_l[t] = 0;
    __syncthreads();
    int cnt = min(bcur[b], BCAP);
    const uint* bp = buck + (uint)b * BCAP;
    for (int i = t; i < cnt; i += 256) atomicAdd(&cnt_l[bp[i] >> 17], 1);
    __syncthreads();
    int node = (b << BSH) + t;
    if (t < 128 && node < N_NODES) deg[node] = cnt_l[t];
}

__global__ void scan1_k(const int* __restrict__ deg, int* __restrict__ rowptr,
                        int* __restrict__ bsums) {
    __shared__ int s[256];
    int b = blockIdx.x, t = threadIdx.x;
    int base = b * SCAN_B + t * 4;
    int v[4];
    int sum = 0;
    #pragma unroll
    for (int j = 0; j < 4; ++j) {
        int idx = base + j;
        v[j] = (idx < N_NODES) ? deg[idx] : 0;
        sum += v[j];
    }
    s[t] = sum;
    __syncthreads();
    for (int off = 1; off < 256; off <<= 1) {
        int x = (t >= off) ? s[t - off] : 0;
        __syncthreads();
        s[t] += x;
        __syncthreads();
    }
    int run = (t > 0) ? s[t - 1] : 0;
    #pragma unroll
    for (int j = 0; j < 4; ++j) {
        run += v[j];
        int idx = base + j;
        if (idx < N_NODES) rowptr[idx + 1] = run;
    }
    if (t == 255) bsums[b] = s[255];
}

__global__ void scan2_k(int* __restrict__ bsums, int nb) {
    __shared__ int s[128];
    int t = threadIdx.x;
    s[t] = (t < nb) ? bsums[t] : 0;
    __syncthreads();
    for (int off = 1; off < 128; off <<= 1) {
        int x = (t >= off) ? s[t - off] : 0;
        __syncthreads();
        s[t] += x;
        __syncthreads();
    }
    if (t < nb) bsums[t] = (t > 0) ? s[t - 1] : 0;
}

__global__ void scan3_k(int* __restrict__ rowptr, const int* __restrict__ bsums) {
    int i = blockIdx.x * blockDim.x + threadIdx.x;
    if (i < N_NODES) rowptr[i + 1] += bsums[i / SCAN_B];
    if (i == 0) rowptr[0] = 0;
}

// phase 2: rank bucket edges into LDS, coalesced writeout.
// col entries are PACKED: bits 0-16 = src, bits 17-20 = dst & 15 (for agg's P build)
__global__ __launch_bounds__(256) void bucket_place2_k(
        const uint* __restrict__ buck, const int* __restrict__ bcur,
        const int* __restrict__ rowptr, int* __restrict__ col) {
    __shared__ int base_n[129];
    __shared__ int fill_l[128];
    __shared__ int col_l[BCAP];
    int b = blockIdx.x, t = threadIdx.x;
    int node0 = b << BSH;
    if (t <= 128) base_n[t] = rowptr[min(node0 + t, N_NODES)];
    if (t < 128) fill_l[t] = 0;
    __syncthreads();
    int pbase = base_n[0];
    int cnt = min(bcur[b], BCAP);
    const uint* bp = buck + (uint)b * BCAP;
    for (int i = t; i < cnt; i += 256) {
        uint p = bp[i];
        int rel = p >> 17;
        int pos = base_n[rel] + atomicAdd(&fill_l[rel], 1) - pbase;
        if (pos < BCAP) col_l[pos] = (int)((p & 0x1FFFFu) | (((uint)rel & 15u) << 17));
    }
    __syncthreads();
    int total = min(base_n[128] - pbase, BCAP);
    for (int i = t; i < total; i += 256) col[pbase + i] = col_l[i];
}

// ---------------- prep: fp32 -> bf16 casts (row-major) ----------------

__global__ void cast_x_k(const float4* __restrict__ in, ushort4* __restrict__ out) {
    int i = blockIdx.x * blockDim.x + threadIdx.x;   // N*C/4 = 3.2M
    if (i < N_NODES * C / 4) {
        float4 v = in[i];
        ushort4 o = { f2b(v.x), f2b(v.y), f2b(v.z), f2b(v.w) };
        out[i] = o;
    }
}

// wcat[o][k] (o-major, [128][256]): k<128 -> Wl[o][k], else Wr[o][k-128]
__global__ void wprep_k(const float* __restrict__ Wl, const float* __restrict__ Wr,
                        ushort* __restrict__ wcat) {
    int i = blockIdx.x * blockDim.x + threadIdx.x;   // 32768
    int o = i >> 8, k = i & 255;
    float v = (k < 128) ? Wl[o * 128 + k] : Wr[o * 128 + (k - 128)];
    wcat[i] = f2b(v);
}

// ---------------- MFMA mean aggregation ----------------
// Wave = 16 dst nodes; edge window processed in uniform 32-edge chunks
// (divergence-free). Per chunk: gather 32 feature rows into LDS E^T_u
// ([64 uch][33] uints: bank-stride 1, conflict-free), build one-hot P in
// B-fragment layout via 2 LDS ops, then 8x mfma_16x16x32_bf16:
// D[ch-tile x dst16] += E^T x P. Mean = acc * (1/deg) in fp32 epilogue
// (numerics identical to scalar bf16-sum-then-divide).
__global__ __launch_bounds__(256) void agg_mfma_k(
        const uint* __restrict__ feat,      // row-major [N][64] uints (bf16x2)
        ushort* __restrict__ outb,          // row-major [N][128] bf16
        const int* __restrict__ rowptr, const int* __restrict__ col) {
    __shared__ uint et[4][64 * 33];         // E^T per wave: 8448 B
    __shared__ ushort pb[4][64 * 8];        // P in B-frag layout: 1 KB per wave
    int wave = threadIdx.x >> 6, lane = threadIdx.x & 63;
    int n0 = (blockIdx.x * 4 + wave) * 16;
    int m = lane & 15, g = lane >> 4;

    // rowptr window (clamped for tail)
    int rp = rowptr[min(n0 + min(lane, 16), N_NODES)];
    int beg = __shfl(rp, 0), end = __shfl(rp, 16);
    int degm = __shfl(rp, m + 1) - __shfl(rp, m);
    float invdeg = 1.0f / (float)max(degm, 1);

    uint* etw = et[wave];
    ushort* pbw = pb[wave];
    uint sel = (m & 1) ? 0x07060302u : 0x05040100u;   // v_perm: pick hi/lo ushorts

    f32x4 acc[8];
    #pragma unroll
    for (int t = 0; t < 8; ++t) acc[t] = (f32x4){0.f, 0.f, 0.f, 0.f};

    for (int e0 = beg; e0 < end; e0 += 32) {
        int cnt = min(32, end - e0);
        // packed col word for this lane's edge (clamped; clamp-dups are masked by P=0)
        int cv = col[e0 + min(lane & 31, cnt - 1)];

        // P: zero own 16B, then scatter 1.0bf16 at [k=e][dst=drel]
        *(bfrag*)&pbw[lane * 8] = (bfrag){0, 0, 0, 0, 0, 0, 0, 0};
        if (lane < cnt) {
            int dr = (cv >> 17) & 15;
            pbw[((lane >> 3) * 16 + dr) * 8 + (lane & 7)] = 0x3F80;  // 1.0 bf16
        }

        // stage E^T: 16 x dwordx2 (rows r = 2q + lane>>5), 32-deep load queue
        #pragma unroll
        for (int q = 0; q < 16; ++q) {
            int r = 2 * q + (lane >> 5);
            uint src = (uint)__shfl(cv, r) & 0x1FFFFu;
            uint2 v = *(const uint2*)(feat + ((size_t)src << 6) + 2 * (lane & 31));
            int uch = 2 * (lane & 31);
            etw[uch * 33 + r] = v.x;
            etw[(uch + 1) * 33 + r] = v.y;
        }
        asm volatile("s_waitcnt lgkmcnt(0)" ::: "memory");

        bfrag bf = *(const bfrag*)&pbw[lane * 8];     // B-frag: P[k][dst]
        #pragma unroll
        for (int t = 0; t < 8; ++t) {
            const uint* ap = etw + (8 * t + (m >> 1)) * 33 + 8 * g;
            uint u0 = ap[0], u1 = ap[1], u2 = ap[2], u3 = ap[3];
            uint u4 = ap[4], u5 = ap[5], u6 = ap[6], u7 = ap[7];
            uint4 av = { __builtin_amdgcn_perm(u1, u0, sel),
                         __builtin_amdgcn_perm(u3, u2, sel),
                         __builtin_amdgcn_perm(u5, u4, sel),
                         __builtin_amdgcn_perm(u7, u6, sel) };
            bfrag af = __builtin_bit_cast(bfrag, av);  // A-frag: E^T[ch][k]
            acc[t] = __builtin_amdgcn_mfma_f32_16x16x32_bf16(af, bf, acc[t], 0, 0, 0);
        }
    }

    // epilogue: mean, stage in LDS (reuse E^T), coalesced bf16 writeout
    ushort* ol = (ushort*)etw;                        // [16 nodes][136 pad]
    #pragma unroll
    for (int t = 0; t < 8; ++t)
        #pragma unroll
        for (int i = 0; i < 4; ++i)
            ol[m * 136 + t * 16 + g * 4 + i] = f2b(acc[t][i] * invdeg);
    asm volatile("s_waitcnt lgkmcnt(0)" ::: "memory");
    #pragma unroll
    for (int q = 0; q < 4; ++q) {
        int row = (q * 64 + lane) >> 4;
        int node = n0 + row;
        uint4 vv = *(const uint4*)&ol[row * 136 + (lane & 15) * 8];
        if (node < N_NODES)
            *(uint4*)&outb[(size_t)node * 128 + (lane & 15) * 8] = vv;
    }
}

// ---------------- fused dual linear via MFMA, W staged in LDS ----------------
template <bool RELU, bool OUT_BF16>
__global__ __launch_bounds__(256) void mfma_lin_k(
        const ushort* __restrict__ A0,      // agg  [M][128] bf16
        const ushort* __restrict__ A1,      // feat [M][128] bf16
        const ushort* __restrict__ W,       // wcat [128][256] bf16
        const float* __restrict__ bias,     // [128]
        void* __restrict__ outp) {
    __shared__ ushort wl[128 * LDW];        // 67.6 KB
    int t = threadIdx.x;

    const bfrag* wg = (const bfrag*)W;
    #pragma unroll
    for (int j = 0; j < 16; ++j) {
        int p = t + j * 256;
        int o = p >> 5, kb = p & 31;
        *(bfrag*)&wl[o * LDW + kb * 8] = wg[p];
    }
    __syncthreads();

    int wave = t >> 6, lane = t & 63;
    int g = lane >> 4, r16 = lane & 15;
    long base = (long)blockIdx.x * 128 + wave * 32;

    const ushort* a0p[2];
    const ushort* a1p[2];
    #pragma unroll
    for (int mt = 0; mt < 2; ++mt) {
        long mrow = base + mt * 16 + r16;
        if (mrow >= N_NODES) mrow = N_NODES - 1;   // clamp loads; stores guarded
        a0p[mt] = A0 + mrow * C + g * 8;
        a1p[mt] = A1 + mrow * C + g * 8;
    }

    f32x4 acc[2][8];
    #pragma unroll
    for (int mt = 0; mt < 2; ++mt)
        #pragma unroll
        for (int nt = 0; nt < 8; ++nt) acc[mt][nt] = (f32x4){0.f, 0.f, 0.f, 0.f};

    #pragma unroll
    for (int c = 0; c < 8; ++c) {
        bfrag a[2];
        #pragma unroll
        for (int mt = 0; mt < 2; ++mt)
            a[mt] = (c < 4) ? *(const bfrag*)(a0p[mt] + c * 32)
                            : *(const bfrag*)(a1p[mt] + (c - 4) * 32);
        #pragma unroll
        for (int nt = 0; nt < 8; ++nt) {
            bfrag b = *(const bfrag*)&wl[(nt * 16 + r16) * LDW + g * 8 + c * 32];
            acc[0][nt] = __builtin_amdgcn_mfma_f32_16x16x32_bf16(a[0], b, acc[0][nt], 0, 0, 0);
            acc[1][nt] = __builtin_amdgcn_mfma_f32_16x16x32_bf16(a[1], b, acc[1][nt], 0, 0, 0);
        }
    }

    #pragma unroll
    for (int nt = 0; nt < 8; ++nt) {
        int o = nt * 16 + r16;
        float bv = bias[o];
        #pragma unroll
        for (int mt = 0; mt < 2; ++mt) {
            #pragma unroll
            for (int i = 0; i < 4; ++i) {
                long orow = base + mt * 16 + g * 4 + i;
                if (orow < N_NODES) {
                    float v = acc[mt][nt][i] + bv;
                    if (RELU) v = fmaxf(v, 0.f);
                    if (OUT_BF16)
                        ((ushort*)outp)[orow * C + o] = f2b(v);
                    else
                        ((float*)outp)[orow * C + o] = v;
                }
            }
        }
    }
}

extern "C" void kernel_launch(void* const* d_in, const int* in_sizes, int n_in,
                              void* d_out, int out_size, void* d_ws, size_t ws_size,
                              hipStream_t stream) {
    const float* x   = (const float*)d_in[0];
    const int* ei    = (const int*)d_in[1];
    const float* W1l = (const float*)d_in[2];
    const float* b1  = (const float*)d_in[3];
    const float* W1r = (const float*)d_in[4];
    const float* W2l = (const float*)d_in[5];
    const float* b2  = (const float*)d_in[6];
    const float* W2r = (const float*)d_in[7];
    float* out       = (float*)d_out;

    char* ws = (char*)d_ws;
    size_t off = 0;
    ushort* xb    = (ushort*)(ws + off); off += (size_t)N_NODES * C * 2;      // 25.6MB
    ushort* aggb  = (ushort*)(ws + off); off += (size_t)N_NODES * C * 2;      // 25.6MB
    ushort* hb    = (ushort*)(ws + off); off += (size_t)N_NODES * C * 2;      // 25.6MB
    uint* buck    = (uint*)hb;   // 8.0MB bucket buffer aliases hb (hb written only after place2)
    ushort* wcat1 = (ushort*)(ws + off); off += (size_t)C * 256 * 2;          // 64KB
    ushort* wcat2 = (ushort*)(ws + off); off += (size_t)C * 256 * 2;          // 64KB
    int* col      = (int*)(ws + off);    off += (size_t)N_EDGES * 4;          // 6.4MB
    int* rowptr   = (int*)(ws + off);    off += (size_t)(N_NODES + 1) * 4;
    int* deg      = (int*)(ws + off);    off += (size_t)NBUCK * 128 * 4;      // 400KB
    int* bcur     = (int*)(ws + off);    off += 1024 * 4;
    int* bsums    = (int*)(ws + off);    off += 1024 * 4;

    int nb = (N_NODES + SCAN_B - 1) / SCAN_B;  // 98

    // --- CSR build: bucket sort with coalesced writeout ---
    hipMemsetAsync(bcur, 0, 1024 * 4, stream);
    bucket_scatter2_k<<<NBLK1, 256, 0, stream>>>(ei, buck, bcur);
    bucket_hist2_k<<<NBUCK, 256, 0, stream>>>(buck, bcur, deg);
    scan1_k<<<nb, 256, 0, stream>>>(deg, rowptr, bsums);
    scan2_k<<<1, 128, 0, stream>>>(bsums, nb);
    scan3_k<<<(N_NODES + 255) / 256, 256, 0, stream>>>(rowptr, bsums);
    bucket_place2_k<<<NBUCK, 256, 0, stream>>>(buck, bcur, rowptr, col);

    // --- prep bf16 (row-major) ---
    cast_x_k<<<(N_NODES * C / 4 + 255) / 256, 256, 0, stream>>>((const float4*)x, (ushort4*)xb);
    wprep_k<<<128, 256, 0, stream>>>(W1l, W1r, wcat1);
    wprep_k<<<128, 256, 0, stream>>>(W2l, W2r, wcat2);

    int lin_blocks = (N_NODES + 127) / 128;   // 782
    int agg_blocks = (N_NODES + 63) / 64;     // 1563 (4 waves x 16 nodes)

    // --- layer 1 ---
    agg_mfma_k<<<agg_blocks, 256, 0, stream>>>((const uint*)xb, aggb, rowptr, col);
    mfma_lin_k<true, true><<<lin_blocks, 256, 0, stream>>>(aggb, xb, wcat1, b1, hb);

    // --- layer 2 ---
    agg_mfma_k<<<agg_blocks, 256, 0, stream>>>((const uint*)hb, aggb, rowptr, col);
    mfma_lin_k<false, false><<<lin_blocks, 256, 0, stream>>>(aggb, hb, wcat2, b2, out);
}

// Round 12
// 256.959 us; speedup vs baseline: 1.1708x; 1.1708x over previous
//
#include <hip/hip_runtime.h>

#define N_NODES 100000
#define N_EDGES 1600000
#define C 128
#define SCAN_B 1024
#define LDW 264            // padded LDS row stride (ushorts) for W staging

// bucket sort params
#define BSH 7              // bucket = dst >> 7 (128 nodes/bucket)
#define NBUCK 782          // ceil(100000 / 128)
#define BCAP 2560          // mean 2048, sigma 45 -> +11 sigma
#define TILE1 8192         // edges per phase-1 block
#define NBLK1 196          // ceil(1.6M / 8192)

typedef __attribute__((ext_vector_type(8))) short bfrag;   // 8 bf16 / 16 B
typedef __attribute__((ext_vector_type(4))) float f32x4;   // MFMA acc

// ---------- bf16 helpers ----------
__device__ __forceinline__ ushort f2b(float x) {
    uint u = __builtin_bit_cast(uint, x);
    u += 0x7fffu + ((u >> 16) & 1u);            // round-to-nearest-even
    return (ushort)(u >> 16);
}
__device__ __forceinline__ float b2f_lo(uint v) {   // low bf16 -> f32 (1 shl)
    return __builtin_bit_cast(float, v << 16);
}
__device__ __forceinline__ float b2f_hi(uint v) {   // high bf16 -> f32 (1 and)
    return __builtin_bit_cast(float, v & 0xFFFF0000u);
}

// ---------------- CSR build: 2-phase bucket sort ----------------

__global__ __launch_bounds__(256) void bucket_scatter2_k(
        const int* __restrict__ ei, uint* __restrict__ buck, int* __restrict__ bcur) {
    __shared__ int hist[NBUCK];
    __shared__ int base_l[NBUCK];
    int t = threadIdx.x;
    int tile0 = blockIdx.x * TILE1;

    for (int i = t; i < NBUCK; i += 256) hist[i] = 0;
    __syncthreads();
    #pragma unroll 4
    for (int j = 0; j < TILE1 / 256; ++j) {
        int e = tile0 + j * 256 + t;
        if (e < N_EDGES) atomicAdd(&hist[ei[N_EDGES + e] >> BSH], 1);
    }
    __syncthreads();
    for (int i = t; i < NBUCK; i += 256) {
        int h = hist[i];
        base_l[i] = h ? atomicAdd(&bcur[i], h) : 0;
    }
    __syncthreads();
    for (int i = t; i < NBUCK; i += 256) hist[i] = 0;
    __syncthreads();
    #pragma unroll 4
    for (int j = 0; j < TILE1 / 256; ++j) {
        int e = tile0 + j * 256 + t;
        if (e < N_EDGES) {
            int src = ei[e];
            int dst = ei[N_EDGES + e];
            int b = dst >> BSH;
            int r = base_l[b] + atomicAdd(&hist[b], 1);
            if (r < BCAP) buck[(uint)b * BCAP + r] = (uint)src | ((uint)(dst & 127) << 17);
        }
    }
}

__global__ __launch_bounds__(256) void bucket_hist2_k(
        const uint* __restrict__ buck, const int* __restrict__ bcur, int* __restrict__ deg) {
    __shared__ int cnt_l[128];
    int b = blockIdx.x, t = threadIdx.x;
    if (t < 128) cnt_l[t] = 0;
    __syncthreads();
    int cnt = min(bcur[b], BCAP);
    const uint* bp = buck + (uint)b * BCAP;
    for (int i = t; i < cnt; i += 256) atomicAdd(&cnt_l[bp[i] >> 17], 1);
    __syncthreads();
    int node = (b << BSH) + t;
    if (t < 128 && node < N_NODES) deg[node] = cnt_l[t];
}

__global__ void scan1_k(const int* __restrict__ deg, int* __restrict__ rowptr,
                        int* __restrict__ bsums) {
    __shared__ int s[256];
    int b = blockIdx.x, t = threadIdx.x;
    int base = b * SCAN_B + t * 4;
    int v[4];
    int sum = 0;
    #pragma unroll
    for (int j = 0; j < 4; ++j) {
        int idx = base + j;
        v[j] = (idx < N_NODES) ? deg[idx] : 0;
        sum += v[j];
    }
    s[t] = sum;
    __syncthreads();
    for (int off = 1; off < 256; off <<= 1) {
        int x = (t >= off) ? s[t - off] : 0;
        __syncthreads();
        s[t] += x;
        __syncthreads();
    }
    int run = (t > 0) ? s[t - 1] : 0;
    #pragma unroll
    for (int j = 0; j < 4; ++j) {
        run += v[j];
        int idx = base + j;
        if (idx < N_NODES) rowptr[idx + 1] = run;
    }
    if (t == 255) bsums[b] = s[255];
}

__global__ void scan2_k(int* __restrict__ bsums, int nb) {
    __shared__ int s[128];
    int t = threadIdx.x;
    s[t] = (t < nb) ? bsums[t] : 0;
    __syncthreads();
    for (int off = 1; off < 128; off <<= 1) {
        int x = (t >= off) ? s[t - off] : 0;
        __syncthreads();
        s[t] += x;
        __syncthreads();
    }
    if (t < nb) bsums[t] = (t > 0) ? s[t - 1] : 0;
}

__global__ void scan3_k(int* __restrict__ rowptr, const int* __restrict__ bsums) {
    int i = blockIdx.x * blockDim.x + threadIdx.x;
    if (i < N_NODES) rowptr[i + 1] += bsums[i / SCAN_B];
    if (i == 0) rowptr[0] = 0;
}

// phase 2: rank bucket edges into LDS, fully-coalesced col writeout (plain src)
__global__ __launch_bounds__(256) void bucket_place2_k(
        const uint* __restrict__ buck, const int* __restrict__ bcur,
        const int* __restrict__ rowptr, int* __restrict__ col) {
    __shared__ int base_n[129];
    __shared__ int fill_l[128];
    __shared__ int col_l[BCAP];
    int b = blockIdx.x, t = threadIdx.x;
    int node0 = b << BSH;
    if (t <= 128) base_n[t] = rowptr[min(node0 + t, N_NODES)];
    if (t < 128) fill_l[t] = 0;
    __syncthreads();
    int pbase = base_n[0];
    int cnt = min(bcur[b], BCAP);
    const uint* bp = buck + (uint)b * BCAP;
    for (int i = t; i < cnt; i += 256) {
        uint p = bp[i];
        int rel = p >> 17;
        int pos = base_n[rel] + atomicAdd(&fill_l[rel], 1) - pbase;
        if (pos < BCAP) col_l[pos] = (int)(p & 0x1FFFFu);
    }
    __syncthreads();
    int total = min(base_n[128] - pbase, BCAP);
    for (int i = t; i < total; i += 256) col[pbase + i] = col_l[i];
}

// ---------------- prep: fp32 -> bf16 casts (row-major) ----------------

__global__ void cast_x_k(const float4* __restrict__ in, ushort4* __restrict__ out) {
    int i = blockIdx.x * blockDim.x + threadIdx.x;   // N*C/4 = 3.2M
    if (i < N_NODES * C / 4) {
        float4 v = in[i];
        ushort4 o = { f2b(v.x), f2b(v.y), f2b(v.z), f2b(v.w) };
        out[i] = o;
    }
}

// wcat[o][k] (o-major, [128][256]): k<128 -> Wl[o][k], else Wr[o][k-128]
__global__ void wprep_k(const float* __restrict__ Wl, const float* __restrict__ Wr,
                        ushort* __restrict__ wcat) {
    int i = blockIdx.x * blockDim.x + threadIdx.x;   // 32768
    int o = i >> 8, k = i & 255;
    float v = (k < 128) ? Wl[o * 128 + k] : Wr[o * 128 + (k - 128)];
    wcat[i] = f2b(v);
}

// ---------------- mean aggregation, bf16 features, scalar col path ----------------
// 1 wave per node; lane = channel pair. Edge indices are WAVE-UNIFORM:
// readfirstlane(beg/end) -> col[ubeg+j] is a uniform address -> compiler emits
// scalar s_load batches (constant cache, SALU pipe) and saddr-form gathers
// (global_load v, v_laneoff, s[row]) -> no per-edge shfl/bpermute, no vector
// address arithmetic. 8-deep unroll keeps 8 gathers in flight.
__global__ __launch_bounds__(256) void agg_bf16_k(
        const uint* __restrict__ feat,      // [N][64] uints (bf16x2)
        uint* __restrict__ outb,            // [N][64]
        const int* __restrict__ rowptr, const int* __restrict__ col) {
    int wave = threadIdx.x >> 6, lane = threadIdx.x & 63;
    int node = blockIdx.x * 4 + wave;
    int beg = __builtin_amdgcn_readfirstlane(rowptr[node]);
    int end = __builtin_amdgcn_readfirstlane(rowptr[node + 1]);
    int deg = end - beg;
    float a0 = 0.f, a1 = 0.f;
    int j = 0;
    for (; j + 8 <= deg; j += 8) {
        uint s0 = (uint)col[beg + j + 0];
        uint s1 = (uint)col[beg + j + 1];
        uint s2 = (uint)col[beg + j + 2];
        uint s3 = (uint)col[beg + j + 3];
        uint s4 = (uint)col[beg + j + 4];
        uint s5 = (uint)col[beg + j + 5];
        uint s6 = (uint)col[beg + j + 6];
        uint s7 = (uint)col[beg + j + 7];
        uint f0 = feat[((size_t)s0 << 6) + lane];
        uint f1 = feat[((size_t)s1 << 6) + lane];
        uint f2 = feat[((size_t)s2 << 6) + lane];
        uint f3 = feat[((size_t)s3 << 6) + lane];
        uint f4 = feat[((size_t)s4 << 6) + lane];
        uint f5 = feat[((size_t)s5 << 6) + lane];
        uint f6 = feat[((size_t)s6 << 6) + lane];
        uint f7 = feat[((size_t)s7 << 6) + lane];
        a0 += b2f_lo(f0) + b2f_lo(f1) + b2f_lo(f2) + b2f_lo(f3)
            + b2f_lo(f4) + b2f_lo(f5) + b2f_lo(f6) + b2f_lo(f7);
        a1 += b2f_hi(f0) + b2f_hi(f1) + b2f_hi(f2) + b2f_hi(f3)
            + b2f_hi(f4) + b2f_hi(f5) + b2f_hi(f6) + b2f_hi(f7);
    }
    for (; j < deg; ++j) {
        uint s = (uint)col[beg + j];
        uint f = feat[((size_t)s << 6) + lane];
        a0 += b2f_lo(f);
        a1 += b2f_hi(f);
    }
    float inv = 1.f / (float)max(deg, 1);
    uint o = (uint)f2b(a0 * inv) | ((uint)f2b(a1 * inv) << 16);
    outb[((uint)node << 6) + lane] = o;
}

// ---------------- fused dual linear via MFMA, W staged in LDS ----------------
template <bool RELU, bool OUT_BF16>
__global__ __launch_bounds__(256) void mfma_lin_k(
        const ushort* __restrict__ A0,      // agg  [M][128] bf16
        const ushort* __restrict__ A1,      // feat [M][128] bf16
        const ushort* __restrict__ W,       // wcat [128][256] bf16
        const float* __restrict__ bias,     // [128]
        void* __restrict__ outp) {
    __shared__ ushort wl[128 * LDW];        // 67.6 KB
    int t = threadIdx.x;

    const bfrag* wg = (const bfrag*)W;
    #pragma unroll
    for (int j = 0; j < 16; ++j) {
        int p = t + j * 256;
        int o = p >> 5, kb = p & 31;
        *(bfrag*)&wl[o * LDW + kb * 8] = wg[p];
    }
    __syncthreads();

    int wave = t >> 6, lane = t & 63;
    int g = lane >> 4, r16 = lane & 15;
    long base = (long)blockIdx.x * 128 + wave * 32;

    const ushort* a0p[2];
    const ushort* a1p[2];
    #pragma unroll
    for (int mt = 0; mt < 2; ++mt) {
        long mrow = base + mt * 16 + r16;
        if (mrow >= N_NODES) mrow = N_NODES - 1;   // clamp loads; stores guarded
        a0p[mt] = A0 + mrow * C + g * 8;
        a1p[mt] = A1 + mrow * C + g * 8;
    }

    f32x4 acc[2][8];
    #pragma unroll
    for (int mt = 0; mt < 2; ++mt)
        #pragma unroll
        for (int nt = 0; nt < 8; ++nt) acc[mt][nt] = (f32x4){0.f, 0.f, 0.f, 0.f};

    #pragma unroll
    for (int c = 0; c < 8; ++c) {
        bfrag a[2];
        #pragma unroll
        for (int mt = 0; mt < 2; ++mt)
            a[mt] = (c < 4) ? *(const bfrag*)(a0p[mt] + c * 32)
                            : *(const bfrag*)(a1p[mt] + (c - 4) * 32);
        #pragma unroll
        for (int nt = 0; nt < 8; ++nt) {
            bfrag b = *(const bfrag*)&wl[(nt * 16 + r16) * LDW + g * 8 + c * 32];
            acc[0][nt] = __builtin_amdgcn_mfma_f32_16x16x32_bf16(a[0], b, acc[0][nt], 0, 0, 0);
            acc[1][nt] = __builtin_amdgcn_mfma_f32_16x16x32_bf16(a[1], b, acc[1][nt], 0, 0, 0);
        }
    }

    #pragma unroll
    for (int nt = 0; nt < 8; ++nt) {
        int o = nt * 16 + r16;
        float bv = bias[o];
        #pragma unroll
        for (int mt = 0; mt < 2; ++mt) {
            #pragma unroll
            for (int i = 0; i < 4; ++i) {
                long orow = base + mt * 16 + g * 4 + i;
                if (orow < N_NODES) {
                    float v = acc[mt][nt][i] + bv;
                    if (RELU) v = fmaxf(v, 0.f);
                    if (OUT_BF16)
                        ((ushort*)outp)[orow * C + o] = f2b(v);
                    else
                        ((float*)outp)[orow * C + o] = v;
                }
            }
        }
    }
}

extern "C" void kernel_launch(void* const* d_in, const int* in_sizes, int n_in,
                              void* d_out, int out_size, void* d_ws, size_t ws_size,
                              hipStream_t stream) {
    const float* x   = (const float*)d_in[0];
    const int* ei    = (const int*)d_in[1];
    const float* W1l = (const float*)d_in[2];
    const float* b1  = (const float*)d_in[3];
    const float* W1r = (const float*)d_in[4];
    const float* W2l = (const float*)d_in[5];
    const float* b2  = (const float*)d_in[6];
    const float* W2r = (const float*)d_in[7];
    float* out       = (float*)d_out;

    char* ws = (char*)d_ws;
    size_t off = 0;
    ushort* xb    = (ushort*)(ws + off); off += (size_t)N_NODES * C * 2;      // 25.6MB
    ushort* aggb  = (ushort*)(ws + off); off += (size_t)N_NODES * C * 2;      // 25.6MB
    ushort* hb    = (ushort*)(ws + off); off += (size_t)N_NODES * C * 2;      // 25.6MB
    uint* buck    = (uint*)hb;   // 8.0MB bucket buffer aliases hb (hb written only after place2)
    ushort* wcat1 = (ushort*)(ws + off); off += (size_t)C * 256 * 2;          // 64KB
    ushort* wcat2 = (ushort*)(ws + off); off += (size_t)C * 256 * 2;          // 64KB
    int* col      = (int*)(ws + off);    off += (size_t)N_EDGES * 4;          // 6.4MB
    int* rowptr   = (int*)(ws + off);    off += (size_t)(N_NODES + 1) * 4;
    int* deg      = (int*)(ws + off);    off += (size_t)NBUCK * 128 * 4;      // 400KB
    int* bcur     = (int*)(ws + off);    off += 1024 * 4;
    int* bsums    = (int*)(ws + off);    off += 1024 * 4;

    int nb = (N_NODES + SCAN_B - 1) / SCAN_B;  // 98

    // --- CSR build: bucket sort with coalesced writeout ---
    hipMemsetAsync(bcur, 0, 1024 * 4, stream);
    bucket_scatter2_k<<<NBLK1, 256, 0, stream>>>(ei, buck, bcur);
    bucket_hist2_k<<<NBUCK, 256, 0, stream>>>(buck, bcur, deg);
    scan1_k<<<nb, 256, 0, stream>>>(deg, rowptr, bsums);
    scan2_k<<<1, 128, 0, stream>>>(bsums, nb);
    scan3_k<<<(N_NODES + 255) / 256, 256, 0, stream>>>(rowptr, bsums);
    bucket_place2_k<<<NBUCK, 256, 0, stream>>>(buck, bcur, rowptr, col);

    // --- prep bf16 ---
    cast_x_k<<<(N_NODES * C / 4 + 255) / 256, 256, 0, stream>>>((const float4*)x, (ushort4*)xb);
    wprep_k<<<128, 256, 0, stream>>>(W1l, W1r, wcat1);
    wprep_k<<<128, 256, 0, stream>>>(W2l, W2r, wcat2);

    int lin_blocks = (N_NODES + 127) / 128;   // 782

    // --- layer 1 ---
    agg_bf16_k<<<N_NODES / 4, 256, 0, stream>>>((const uint*)xb, (uint*)aggb, rowptr, col);
    mfma_lin_k<true, true><<<lin_blocks, 256, 0, stream>>>(aggb, xb, wcat1, b1, hb);

    // --- layer 2 ---
    agg_bf16_k<<<N_NODES / 4, 256, 0, stream>>>((const uint*)hb, (uint*)aggb, rowptr, col);
    mfma_lin_k<false, false><<<lin_blocks, 256, 0, stream>>>(aggb, hb, wcat2, b2, out);
}